// Round 1
// baseline (1806.741 us; speedup 1.0000x reference)
//
#include <hip/hip_runtime.h>

#define DIM 64

// out = h  (residual init), vectorized float4 copy
__global__ void init_out_kernel(const float* __restrict__ h,
                                float* __restrict__ out, int n4) {
    int i = blockIdx.x * blockDim.x + threadIdx.x;
    if (i < n4) {
        reinterpret_cast<float4*>(out)[i] =
            reinterpret_cast<const float4*>(h)[i];
    }
}

// One edge per 16 threads; each thread handles 4 consecutive floats (float4).
// msg = h[src]*weight[rel] + e*attention[rel]; atomicAdd into out[dst].
__global__ void edge_msg_kernel(const float* __restrict__ h,
                                const float* __restrict__ e,
                                const float* __restrict__ w,
                                const float* __restrict__ att,
                                const int* __restrict__ src,
                                const int* __restrict__ dst,
                                const int* __restrict__ rel,
                                float* __restrict__ out, int E) {
    long long tid = (long long)blockIdx.x * blockDim.x + threadIdx.x;
    int k = (int)(tid >> 4);           // edge index
    if (k >= E) return;
    int q = ((int)tid & 15) << 2;      // float offset within the D=64 row

    int s = src[k];
    int d = dst[k];
    int r = rel[k];

    const float4 hv  = *reinterpret_cast<const float4*>(h   + (size_t)s * DIM + q);
    const float4 ev  = *reinterpret_cast<const float4*>(e   + (size_t)k * DIM + q);
    const float4 wv  = *reinterpret_cast<const float4*>(w   + (size_t)r * DIM + q);
    const float4 av  = *reinterpret_cast<const float4*>(att + (size_t)r * DIM + q);

    float4 m;
    m.x = hv.x * wv.x + ev.x * av.x;
    m.y = hv.y * wv.y + ev.y * av.y;
    m.z = hv.z * wv.z + ev.z * av.z;
    m.w = hv.w * wv.w + ev.w * av.w;

    float* o = out + (size_t)d * DIM + q;
    atomicAdd(o + 0, m.x);
    atomicAdd(o + 1, m.y);
    atomicAdd(o + 2, m.z);
    atomicAdd(o + 3, m.w);
}

extern "C" void kernel_launch(void* const* d_in, const int* in_sizes, int n_in,
                              void* d_out, int out_size, void* d_ws, size_t ws_size,
                              hipStream_t stream) {
    const float* h   = (const float*)d_in[0];
    const float* e   = (const float*)d_in[1];
    const float* w   = (const float*)d_in[2];
    const float* att = (const float*)d_in[3];
    const int* src   = (const int*)d_in[4];
    const int* dst   = (const int*)d_in[5];
    const int* rel   = (const int*)d_in[6];
    float* out       = (float*)d_out;

    const int N = in_sizes[0] / DIM;   // 100000
    const int E = in_sizes[1] / DIM;   // 1600000

    // 1) out = h (d_out is poisoned to 0xAA before every launch)
    int n4 = N * (DIM / 4);
    init_out_kernel<<<(n4 + 255) / 256, 256, 0, stream>>>(h, out, n4);

    // 2) per-edge messages with atomic scatter-add
    long long total = (long long)E * 16;
    int blocks = (int)((total + 255) / 256);
    edge_msg_kernel<<<blocks, 256, 0, stream>>>(h, e, w, att, src, dst, rel, out, E);
}

// Round 2
// 861.018 us; speedup vs baseline: 2.0984x; 2.0984x over previous
//
#include <hip/hip_runtime.h>

#define DIM 64
#define SCAN_BLOCK 256
#define ELEMS_PER_THREAD 8
#define ELEMS_PER_BLOCK (SCAN_BLOCK * ELEMS_PER_THREAD)  // 2048

// ---------- CSR build ----------

__global__ void hist_kernel(const int* __restrict__ dst, int* __restrict__ counts, int E) {
    int k = blockIdx.x * blockDim.x + threadIdx.x;
    if (k < E) atomicAdd(&counts[dst[k]], 1);
}

__global__ void scan1_kernel(const int* __restrict__ counts, int* __restrict__ offsets,
                             int* __restrict__ bsums, int N) {
    __shared__ int lds[SCAN_BLOCK];
    int base = blockIdx.x * ELEMS_PER_BLOCK + threadIdx.x * ELEMS_PER_THREAD;
    int v[ELEMS_PER_THREAD];
    int tsum = 0;
#pragma unroll
    for (int i = 0; i < ELEMS_PER_THREAD; ++i) {
        int idx = base + i;
        v[i] = (idx < N) ? counts[idx] : 0;
        tsum += v[i];
    }
    lds[threadIdx.x] = tsum;
    __syncthreads();
    // Hillis-Steele inclusive scan over 256 thread-totals
    for (int off = 1; off < SCAN_BLOCK; off <<= 1) {
        int t = (threadIdx.x >= off) ? lds[threadIdx.x - off] : 0;
        __syncthreads();
        lds[threadIdx.x] += t;
        __syncthreads();
    }
    int incl = lds[threadIdx.x];
    int running = incl - tsum;  // exclusive base for this thread
#pragma unroll
    for (int i = 0; i < ELEMS_PER_THREAD; ++i) {
        int idx = base + i;
        if (idx < N) offsets[idx] = running;
        running += v[i];
    }
    if (threadIdx.x == SCAN_BLOCK - 1) bsums[blockIdx.x] = incl;  // block total
}

__global__ void scan2_kernel(int* __restrict__ bsums, int nb) {
    if (blockIdx.x == 0 && threadIdx.x == 0) {
        int run = 0;
        for (int i = 0; i < nb; ++i) { int c = bsums[i]; bsums[i] = run; run += c; }
    }
}

__global__ void scan3_kernel(int* __restrict__ offsets, int* __restrict__ cursor,
                             const int* __restrict__ bsums, int N, int E) {
    int i = blockIdx.x * blockDim.x + threadIdx.x;
    if (i < N) {
        int o = offsets[i] + bsums[i / ELEMS_PER_BLOCK];
        offsets[i] = o;
        cursor[i] = o;
    }
    if (i == 0) offsets[N] = E;
}

__global__ void scatter_kernel(const int* __restrict__ dst, int* __restrict__ cursor,
                               int* __restrict__ perm, int E) {
    int k = blockIdx.x * blockDim.x + threadIdx.x;
    if (k < E) {
        int p = atomicAdd(&cursor[dst[k]], 1);
        perm[p] = k;
    }
}

// ---------- gather: one wave per node, lane = feature dim ----------

__global__ void gather_kernel(const float* __restrict__ h, const float* __restrict__ e,
                              const float* __restrict__ w, const float* __restrict__ att,
                              const int* __restrict__ src, const int* __restrict__ rel,
                              const int* __restrict__ offsets, const int* __restrict__ perm,
                              float* __restrict__ out, int N) {
    int wave = (int)(((long long)blockIdx.x * blockDim.x + threadIdx.x) >> 6);
    int lane = threadIdx.x & 63;
    if (wave >= N) return;

    int start = offsets[wave];
    int end   = offsets[wave + 1];
    float acc = h[(size_t)wave * DIM + lane];

    for (int b = start; b < end; b += 64) {
        int cnt = min(64, end - b);
        int kk = 0, ss = 0, rr = 0;
        if (lane < cnt) {
            kk = perm[b + lane];   // coalesced batch load of edge ids
            ss = src[kk];
            rr = rel[kk];
        }
        for (int j = 0; j < cnt; ++j) {
            int k = __shfl(kk, j);
            int s = __shfl(ss, j);
            int r = __shfl(rr, j);
            acc += h[(size_t)s * DIM + lane] * w[(size_t)r * DIM + lane]
                 + e[(size_t)k * DIM + lane] * att[(size_t)r * DIM + lane];
        }
    }
    out[(size_t)wave * DIM + lane] = acc;
}

// ---------- fallback (atomic path) if workspace too small ----------

__global__ void init_out_kernel(const float* __restrict__ h, float* __restrict__ out, int n4) {
    int i = blockIdx.x * blockDim.x + threadIdx.x;
    if (i < n4)
        reinterpret_cast<float4*>(out)[i] = reinterpret_cast<const float4*>(h)[i];
}

__global__ void edge_msg_kernel(const float* __restrict__ h, const float* __restrict__ e,
                                const float* __restrict__ w, const float* __restrict__ att,
                                const int* __restrict__ src, const int* __restrict__ dst,
                                const int* __restrict__ rel, float* __restrict__ out, int E) {
    long long tid = (long long)blockIdx.x * blockDim.x + threadIdx.x;
    int k = (int)(tid >> 4);
    if (k >= E) return;
    int q = ((int)tid & 15) << 2;
    int s = src[k], d = dst[k], r = rel[k];
    const float4 hv  = *reinterpret_cast<const float4*>(h   + (size_t)s * DIM + q);
    const float4 ev  = *reinterpret_cast<const float4*>(e   + (size_t)k * DIM + q);
    const float4 wv  = *reinterpret_cast<const float4*>(w   + (size_t)r * DIM + q);
    const float4 av  = *reinterpret_cast<const float4*>(att + (size_t)r * DIM + q);
    float4 m;
    m.x = hv.x * wv.x + ev.x * av.x;
    m.y = hv.y * wv.y + ev.y * av.y;
    m.z = hv.z * wv.z + ev.z * av.z;
    m.w = hv.w * wv.w + ev.w * av.w;
    float* o = out + (size_t)d * DIM + q;
    atomicAdd(o + 0, m.x);
    atomicAdd(o + 1, m.y);
    atomicAdd(o + 2, m.z);
    atomicAdd(o + 3, m.w);
}

extern "C" void kernel_launch(void* const* d_in, const int* in_sizes, int n_in,
                              void* d_out, int out_size, void* d_ws, size_t ws_size,
                              hipStream_t stream) {
    const float* h   = (const float*)d_in[0];
    const float* e   = (const float*)d_in[1];
    const float* w   = (const float*)d_in[2];
    const float* att = (const float*)d_in[3];
    const int* src   = (const int*)d_in[4];
    const int* dst   = (const int*)d_in[5];
    const int* rel   = (const int*)d_in[6];
    float* out       = (float*)d_out;

    const int N = in_sizes[0] / DIM;   // 100000
    const int E = in_sizes[1] / DIM;   // 1600000

    const int nb = (N + ELEMS_PER_BLOCK - 1) / ELEMS_PER_BLOCK;   // scan blocks
    const int nb_pad = (nb + 63) & ~63;

    // workspace layout (ints): counts[N] | offsets[N+1] | cursor[N] | bsums[nb_pad] | perm[E]
    size_t need = ((size_t)3 * N + 1 + nb_pad + E) * sizeof(int);

    if (ws_size < need) {
        // fallback: atomic scatter-add path (correct, slower)
        int n4 = N * (DIM / 4);
        init_out_kernel<<<(n4 + 255) / 256, 256, 0, stream>>>(h, out, n4);
        long long total = (long long)E * 16;
        int blocks = (int)((total + 255) / 256);
        edge_msg_kernel<<<blocks, 256, 0, stream>>>(h, e, w, att, src, dst, rel, out, E);
        return;
    }

    int* counts  = (int*)d_ws;
    int* offsets = counts + N;
    int* cursor  = offsets + N + 1;
    int* bsums   = cursor + N;
    int* perm    = bsums + nb_pad;

    hipMemsetAsync(counts, 0, (size_t)N * sizeof(int), stream);

    hist_kernel<<<(E + 255) / 256, 256, 0, stream>>>(dst, counts, E);
    scan1_kernel<<<nb, SCAN_BLOCK, 0, stream>>>(counts, offsets, bsums, N);
    scan2_kernel<<<1, 64, 0, stream>>>(bsums, nb);
    scan3_kernel<<<(N + 255) / 256, 256, 0, stream>>>(offsets, cursor, bsums, N, E);
    scatter_kernel<<<(E + 255) / 256, 256, 0, stream>>>(dst, cursor, perm, E);

    long long threads = (long long)N * 64;
    int gblocks = (int)((threads + 255) / 256);
    gather_kernel<<<gblocks, 256, 0, stream>>>(h, e, w, att, src, rel, offsets, perm, out, N);
}

// Round 3
// 796.073 us; speedup vs baseline: 2.2696x; 1.0816x over previous
//
#include <hip/hip_runtime.h>

#define DIM 64
#define SCAN_BLOCK 256
#define ELEMS_PER_THREAD 8
#define ELEMS_PER_BLOCK (SCAN_BLOCK * ELEMS_PER_THREAD)  // 2048

// ---------- CSR build ----------

// counts aliases `cursor` (zeroed before, overwritten by scan3 afterwards)
__global__ void hist_kernel(const int* __restrict__ dst, int* __restrict__ counts, int E) {
    int k = blockIdx.x * blockDim.x + threadIdx.x;
    if (k < E) atomicAdd(&counts[dst[k]], 1);
}

__global__ void scan1_kernel(const int* __restrict__ counts, int* __restrict__ offsets,
                             int* __restrict__ bsums, int N) {
    __shared__ int lds[SCAN_BLOCK];
    int base = blockIdx.x * ELEMS_PER_BLOCK + threadIdx.x * ELEMS_PER_THREAD;
    int v[ELEMS_PER_THREAD];
    int tsum = 0;
#pragma unroll
    for (int i = 0; i < ELEMS_PER_THREAD; ++i) {
        int idx = base + i;
        v[i] = (idx < N) ? counts[idx] : 0;
        tsum += v[i];
    }
    lds[threadIdx.x] = tsum;
    __syncthreads();
    for (int off = 1; off < SCAN_BLOCK; off <<= 1) {
        int t = (threadIdx.x >= off) ? lds[threadIdx.x - off] : 0;
        __syncthreads();
        lds[threadIdx.x] += t;
        __syncthreads();
    }
    int incl = lds[threadIdx.x];
    int running = incl - tsum;
#pragma unroll
    for (int i = 0; i < ELEMS_PER_THREAD; ++i) {
        int idx = base + i;
        if (idx < N) offsets[idx] = running;
        running += v[i];
    }
    if (threadIdx.x == SCAN_BLOCK - 1) bsums[blockIdx.x] = incl;
}

// wave-parallel exclusive scan of block sums (nb <= 64 chunks per pass, with carry)
__global__ void scan2_kernel(int* __restrict__ bsums, int nb) {
    int lane = threadIdx.x;  // 64 threads
    int carry = 0;
    for (int base = 0; base < nb; base += 64) {
        int i = base + lane;
        int orig = (i < nb) ? bsums[i] : 0;
        int v = orig;
        for (int off = 1; off < 64; off <<= 1) {
            int t = __shfl_up(v, off);
            if (lane >= off) v += t;
        }
        if (i < nb) bsums[i] = carry + v - orig;  // exclusive
        carry += __shfl(v, 63);
    }
}

__global__ void scan3_kernel(int* __restrict__ offsets, int* __restrict__ cursor,
                             const int* __restrict__ bsums, int N, int E) {
    int i = blockIdx.x * blockDim.x + threadIdx.x;
    if (i < N) {
        int o = offsets[i] + bsums[i / ELEMS_PER_BLOCK];
        offsets[i] = o;
        cursor[i] = o;
    }
    if (i == 0) offsets[N] = E;
}

// pack {k, src[k], rel[k]} so the gather needs no dependent index loads
__global__ void scatter_kernel(const int* __restrict__ dst, const int* __restrict__ src,
                               const int* __restrict__ rel, int* __restrict__ cursor,
                               int4* __restrict__ perm4, int E) {
    int k = blockIdx.x * blockDim.x + threadIdx.x;
    if (k < E) {
        int p = atomicAdd(&cursor[dst[k]], 1);
        perm4[p] = make_int4(k, src[k], rel[k], 0);
    }
}

// ---------- gather: one wave per node, lane = feature dim, 4-edge unroll ----------

__global__ void gather_kernel(const float* __restrict__ h, const float* __restrict__ e,
                              const float* __restrict__ w, const float* __restrict__ att,
                              const int* __restrict__ offsets, const int4* __restrict__ perm4,
                              float* __restrict__ out, int N) {
    int wave = (int)(((long long)blockIdx.x * blockDim.x + threadIdx.x) >> 6);
    int lane = threadIdx.x & 63;
    if (wave >= N) return;

    int start = offsets[wave];
    int end   = offsets[wave + 1];
    float acc = h[(size_t)wave * DIM + lane];

    for (int b = start; b < end; b += 64) {
        int cnt = min(64, end - b);
        int4 ent = make_int4(0, 0, 0, 0);
        if (lane < cnt) ent = perm4[b + lane];  // one coalesced 16B load per edge

        int j = 0;
        for (; j + 4 <= cnt; j += 4) {
            int k0 = __shfl(ent.x, j + 0), s0 = __shfl(ent.y, j + 0), r0 = __shfl(ent.z, j + 0);
            int k1 = __shfl(ent.x, j + 1), s1 = __shfl(ent.y, j + 1), r1 = __shfl(ent.z, j + 1);
            int k2 = __shfl(ent.x, j + 2), s2 = __shfl(ent.y, j + 2), r2 = __shfl(ent.z, j + 2);
            int k3 = __shfl(ent.x, j + 3), s3 = __shfl(ent.y, j + 3), r3 = __shfl(ent.z, j + 3);

            float e0 = e[(size_t)k0 * DIM + lane], h0 = h[(size_t)s0 * DIM + lane];
            float w0 = w[(size_t)r0 * DIM + lane], a0 = att[(size_t)r0 * DIM + lane];
            float e1 = e[(size_t)k1 * DIM + lane], h1 = h[(size_t)s1 * DIM + lane];
            float w1 = w[(size_t)r1 * DIM + lane], a1 = att[(size_t)r1 * DIM + lane];
            float e2 = e[(size_t)k2 * DIM + lane], h2 = h[(size_t)s2 * DIM + lane];
            float w2 = w[(size_t)r2 * DIM + lane], a2 = att[(size_t)r2 * DIM + lane];
            float e3 = e[(size_t)k3 * DIM + lane], h3 = h[(size_t)s3 * DIM + lane];
            float w3 = w[(size_t)r3 * DIM + lane], a3 = att[(size_t)r3 * DIM + lane];

            acc += h0 * w0 + e0 * a0;
            acc += h1 * w1 + e1 * a1;
            acc += h2 * w2 + e2 * a2;
            acc += h3 * w3 + e3 * a3;
        }
        for (; j < cnt; ++j) {
            int k = __shfl(ent.x, j), s = __shfl(ent.y, j), r = __shfl(ent.z, j);
            acc += h[(size_t)s * DIM + lane] * w[(size_t)r * DIM + lane]
                 + e[(size_t)k * DIM + lane] * att[(size_t)r * DIM + lane];
        }
    }
    out[(size_t)wave * DIM + lane] = acc;
}

// ---------- fallback (atomic path) if workspace too small ----------

__global__ void init_out_kernel(const float* __restrict__ h, float* __restrict__ out, int n4) {
    int i = blockIdx.x * blockDim.x + threadIdx.x;
    if (i < n4)
        reinterpret_cast<float4*>(out)[i] = reinterpret_cast<const float4*>(h)[i];
}

__global__ void edge_msg_kernel(const float* __restrict__ h, const float* __restrict__ e,
                                const float* __restrict__ w, const float* __restrict__ att,
                                const int* __restrict__ src, const int* __restrict__ dst,
                                const int* __restrict__ rel, float* __restrict__ out, int E) {
    long long tid = (long long)blockIdx.x * blockDim.x + threadIdx.x;
    int k = (int)(tid >> 4);
    if (k >= E) return;
    int q = ((int)tid & 15) << 2;
    int s = src[k], d = dst[k], r = rel[k];
    const float4 hv  = *reinterpret_cast<const float4*>(h   + (size_t)s * DIM + q);
    const float4 ev  = *reinterpret_cast<const float4*>(e   + (size_t)k * DIM + q);
    const float4 wv  = *reinterpret_cast<const float4*>(w   + (size_t)r * DIM + q);
    const float4 av  = *reinterpret_cast<const float4*>(att + (size_t)r * DIM + q);
    float4 m;
    m.x = hv.x * wv.x + ev.x * av.x;
    m.y = hv.y * wv.y + ev.y * av.y;
    m.z = hv.z * wv.z + ev.z * av.z;
    m.w = hv.w * wv.w + ev.w * av.w;
    float* o = out + (size_t)d * DIM + q;
    atomicAdd(o + 0, m.x);
    atomicAdd(o + 1, m.y);
    atomicAdd(o + 2, m.z);
    atomicAdd(o + 3, m.w);
}

extern "C" void kernel_launch(void* const* d_in, const int* in_sizes, int n_in,
                              void* d_out, int out_size, void* d_ws, size_t ws_size,
                              hipStream_t stream) {
    const float* h   = (const float*)d_in[0];
    const float* e   = (const float*)d_in[1];
    const float* w   = (const float*)d_in[2];
    const float* att = (const float*)d_in[3];
    const int* src   = (const int*)d_in[4];
    const int* dst   = (const int*)d_in[5];
    const int* rel   = (const int*)d_in[6];
    float* out       = (float*)d_out;

    const int N = in_sizes[0] / DIM;   // 100000
    const int E = in_sizes[1] / DIM;   // 1600000

    const int nb = (N + ELEMS_PER_BLOCK - 1) / ELEMS_PER_BLOCK;
    const int nb_pad = (nb + 63) & ~63;

    // layout: perm4[E] (16B-aligned, first) | offsets[N+1] | cursor[N] | bsums[nb_pad]
    size_t need = (size_t)E * 16 + ((size_t)2 * N + 1 + nb_pad) * sizeof(int);

    if (ws_size < need) {
        int n4 = N * (DIM / 4);
        init_out_kernel<<<(n4 + 255) / 256, 256, 0, stream>>>(h, out, n4);
        long long total = (long long)E * 16;
        int blocks = (int)((total + 255) / 256);
        edge_msg_kernel<<<blocks, 256, 0, stream>>>(h, e, w, att, src, dst, rel, out, E);
        return;
    }

    int4* perm4  = (int4*)d_ws;
    int* offsets = (int*)(perm4 + E);
    int* cursor  = offsets + N + 1;
    int* bsums   = cursor + N;

    // counts aliases cursor
    hipMemsetAsync(cursor, 0, (size_t)N * sizeof(int), stream);

    hist_kernel<<<(E + 255) / 256, 256, 0, stream>>>(dst, cursor, E);
    scan1_kernel<<<nb, SCAN_BLOCK, 0, stream>>>(cursor, offsets, bsums, N);
    scan2_kernel<<<1, 64, 0, stream>>>(bsums, nb);
    scan3_kernel<<<(N + 255) / 256, 256, 0, stream>>>(offsets, cursor, bsums, N, E);
    scatter_kernel<<<(E + 255) / 256, 256, 0, stream>>>(dst, src, rel, cursor, perm4, E);

    long long threads = (long long)N * 64;
    int gblocks = (int)((threads + 255) / 256);
    gather_kernel<<<gblocks, 256, 0, stream>>>(h, e, w, att, offsets, perm4, out, N);
}